// Round 2
// baseline (1229.721 us; speedup 1.0000x reference)
//
#include <hip/hip_runtime.h>
#include <hip/hip_bf16.h>

typedef __attribute__((ext_vector_type(8))) short short8;
typedef __attribute__((ext_vector_type(4))) float floatx4;

constexpr int K_TOT = 4096;
constexpr int N_TOT = 11008;
constexpr int NPACK = N_TOT / 8;     // 1376 packed int32 cols
constexpr int BM = 128, BN = 128, BK = 32;
constexpr int LDST = 40;             // LDS row stride (bf16 elems): 32 + 8 pad
constexpr int NKT = K_TOT / BK;      // 128 K-tiles
constexpr int NBN = N_TOT / BN;      // 86

__device__ __forceinline__ unsigned short f2bf(float f) {
  __hip_bfloat16 h = __float2bfloat16(f);
  return __builtin_bit_cast(unsigned short, h);
}

__global__ __launch_bounds__(256, 2)
void awq_gemm(const float* __restrict__ X,
              const int* __restrict__ QW,
              const int* __restrict__ QZ,
              const float* __restrict__ SC,   // harness passes fp16 inputs as fp32
              const float* __restrict__ BI,   // harness passes fp16 inputs as fp32
              float* __restrict__ OUT)
{
  __shared__ __align__(16) unsigned short As[BM * LDST];
  __shared__ __align__(16) unsigned short Bs[BN * LDST];

  const int tid  = threadIdx.x;
  const int lane = tid & 63;
  const int wid  = tid >> 6;      // 4 waves: 2x2 wave grid, 64x64 out each
  const int wm   = wid >> 1;
  const int wn   = wid & 1;

  // XCD-aware bijective swizzle: grid 5504 = 8 * 688
  const int cpx = gridDim.x >> 3;
  const int bid = blockIdx.x;
  const int lg  = (bid & 7) * cpx + (bid >> 3);
  const int m0  = (lg / NBN) * BM;
  const int n0  = (lg % NBN) * BN;

  // A staging: 2 threads per row, 16 fp32 each
  const int a_row = tid >> 1;
  const int a_col = (tid & 1) << 4;
  const float* aptr = X + (size_t)(m0 + a_row) * K_TOT + a_col;

  // B staging: thread = (packed col jc, k-pair kp); 2 int32 -> 16 bf16
  const int jc   = tid & 15;      // 0..15 packed col within tile
  const int kp   = tid >> 4;      // 0..15 -> k = 2*kp, 2*kp+1
  const int nloc = jc << 3;       // local n base of this thread's 8 outputs
  const int* qptr = QW + (size_t)(2 * kp) * NPACK + (n0 >> 3) + jc;
  const int* zptr = QZ + (n0 >> 3) + jc;
  const float* sptr = SC + n0 + nloc;

  floatx4 acc[4][4];
  #pragma unroll
  for (int i = 0; i < 4; ++i)
    #pragma unroll
    for (int j = 0; j < 4; ++j)
      acc[i][j] = (floatx4){0.f, 0.f, 0.f, 0.f};

  // prologue: prefetch tile 0 into registers
  floatx4 apre[4];
  #pragma unroll
  for (int i = 0; i < 4; ++i)
    apre[i] = *reinterpret_cast<const floatx4*>(aptr + 4 * i);
  int qa = qptr[0];
  int qb = qptr[NPACK];

  float sc8[8], zs8[8];

  const int frow  = lane & 15;
  const int koff  = (lane >> 4) << 3;     // 0,8,16,24
  const int arow0 = wm * 64 + frow;
  const int brow0 = wn * 64 + frow;

  for (int t = 0; t < NKT; ++t) {
    // per-group (128 rows = 4 tiles) zero/scale precompute
    if ((t & 3) == 0) {
      const int g = t >> 2;
      const int qz = zptr[(size_t)g * NPACK];
      const floatx4* sp = reinterpret_cast<const floatx4*>(sptr + (size_t)g * N_TOT);
      floatx4 s0 = sp[0], s1 = sp[1];
      #pragma unroll
      for (int i = 0; i < 4; ++i) { sc8[i] = s0[i]; sc8[4 + i] = s1[i]; }
      constexpr int SH[8] = {0, 16, 4, 20, 8, 24, 12, 28};  // 4*AWQ_REVERSE
      #pragma unroll
      for (int c = 0; c < 8; ++c)
        zs8[c] = (float)((qz >> SH[c]) & 15) * sc8[c];
    }

    // ---- write prefetched A regs -> LDS (fp32 -> bf16) ----
    {
      unsigned short tmp[16];
      #pragma unroll
      for (int i = 0; i < 4; ++i)
        #pragma unroll
        for (int j = 0; j < 4; ++j)
          tmp[4 * i + j] = f2bf(apre[i][j]);
      short8 lo, hi;
      #pragma unroll
      for (int j = 0; j < 8; ++j) { lo[j] = (short)tmp[j]; hi[j] = (short)tmp[8 + j]; }
      *reinterpret_cast<short8*>(&As[a_row * LDST + a_col])     = lo;
      *reinterpret_cast<short8*>(&As[a_row * LDST + a_col + 8]) = hi;
    }

    // ---- dequant prefetched B regs -> LDS (k-transposed, swizzled) ----
    {
      constexpr int SH[8] = {0, 16, 4, 20, 8, 24, 12, 28};
      #pragma unroll
      for (int c = 0; c < 8; ++c) {
        float wa = (float)((qa >> SH[c]) & 15) * sc8[c] - zs8[c];
        float wb = (float)((qb >> SH[c]) & 15) * sc8[c] - zs8[c];
        unsigned int pair = (unsigned int)f2bf(wa) | ((unsigned int)f2bf(wb) << 16);
        const int n  = nloc + c;
        const int kk = (2 * kp) ^ (((n >> 3) & 3) << 3);   // 16B-granule XOR swizzle
        *reinterpret_cast<unsigned int*>(&Bs[n * LDST + kk]) = pair;
      }
    }

    __syncthreads();

    // ---- prefetch next tile into registers (hides under MFMA) ----
    if (t + 1 < NKT) {
      const float* ap = aptr + (t + 1) * BK;
      #pragma unroll
      for (int i = 0; i < 4; ++i)
        apre[i] = *reinterpret_cast<const floatx4*>(ap + 4 * i);
      const int* qp = qptr + (size_t)(t + 1) * BK * NPACK;
      qa = qp[0];
      qb = qp[NPACK];
    }

    // ---- fragment reads + 16 MFMA ----
    short8 af[4], bfv[4];
    #pragma unroll
    for (int mf = 0; mf < 4; ++mf)
      af[mf] = *reinterpret_cast<const short8*>(&As[(arow0 + mf * 16) * LDST + koff]);
    #pragma unroll
    for (int nf = 0; nf < 4; ++nf) {
      const int n  = brow0 + nf * 16;
      const int kk = koff ^ (((n >> 3) & 3) << 3);
      bfv[nf] = *reinterpret_cast<const short8*>(&Bs[n * LDST + kk]);
    }
    #pragma unroll
    for (int mf = 0; mf < 4; ++mf)
      #pragma unroll
      for (int nf = 0; nf < 4; ++nf)
        acc[mf][nf] = __builtin_amdgcn_mfma_f32_16x16x32_bf16(
            af[mf], bfv[nf], acc[mf][nf], 0, 0, 0);

    __syncthreads();
  }

  // ---- epilogue: bias + fp32 store ----
  // C/D layout: col = lane&15, row = (lane>>4)*4 + reg
  const int ocol = lane & 15;
  const int orow = (lane >> 4) << 2;
  #pragma unroll
  for (int nf = 0; nf < 4; ++nf) {
    const int gn = n0 + wn * 64 + nf * 16 + ocol;
    const float bv = BI[gn];
    #pragma unroll
    for (int mf = 0; mf < 4; ++mf) {
      const size_t gm = (size_t)(m0 + wm * 64 + mf * 16 + orow);
      #pragma unroll
      for (int j = 0; j < 4; ++j)
        OUT[(gm + j) * (size_t)N_TOT + gn] = acc[mf][nf][j] + bv;
    }
  }
}

extern "C" void kernel_launch(void* const* d_in, const int* in_sizes, int n_in,
                              void* d_out, int out_size, void* d_ws, size_t ws_size,
                              hipStream_t stream) {
  const float* x    = (const float*)d_in[0];
  const int*   qw   = (const int*)d_in[1];
  const int*   qz   = (const int*)d_in[2];
  const float* sc   = (const float*)d_in[3];
  const float* bias = (const float*)d_in[4];
  float* out = (float*)d_out;

  const int M = 8192;                   // 4 * 2048
  dim3 grid((M / BM) * NBN);            // 64 * 86 = 5504 (divisible by 8)
  awq_gemm<<<grid, 256, 0, stream>>>(x, qw, qz, sc, bias, out);
}